// Round 6
// baseline (1068.967 us; speedup 1.0000x reference)
//
#include <hip/hip_runtime.h>
#include <math.h>

#define L_SEQ 4096
#define BSZ   4
#define DIM   1024
#define NDIM  16
#define BD    (BSZ*DIM)
#define CHUNK 64      // outputs per wave
#define HALO  64      // warm-up length; q^64 <= 0.008 worst-case -> err ~0.03 << 0.357

// Fused bidirectional 16-state EMA, halo-truncated, no transposes.
// Wave = (b, 64-wide d-tile, 64-long L-chunk). Lane = d within tile, so every
// global access is a coalesced 256B transaction in the native (L,B,D) layout.
// No LDS, no shuffles, no syncthreads - waves fully independent.
__global__ __launch_bounds__(256) void k_ema_fused(
    const float* __restrict__ x,
    const float* __restrict__ delta,
    const float* __restrict__ alpha,
    const float* __restrict__ beta,
    const float* __restrict__ gamma,
    const float* __restrict__ omega,
    float* __restrict__ out)
{
    const int lane  = threadIdx.x & 63;
    const int wave  = threadIdx.x >> 6;        // 0..3
    const int dtile = blockIdx.x & 15;         // 16 tiles of 64 d's
    const int b     = (blockIdx.x >> 4) & 3;   // batch
    const int lgrp  = blockIdx.x >> 6;         // 0..15 groups of 4 chunks
    const int chunk = lgrp * 4 + wave;         // 0..63
    const int i0    = chunk * CHUNK;
    const int dg    = dtile * 64 + lane;       // 0..1023
    const int col   = b * DIM + dg;            // column in (L, B*D)

    const float omega_d = omega[dg];

    float acc[CHUNK];
    float h[NDIM], q[NDIM], wt[NDIM];

    // ============ forward direction: params row dg ============
    #pragma unroll
    for (int n = 0; n < NDIM; ++n) {
        const int idx = dg * NDIM + n;
        const float p  = 1.0f / (1.0f + __expf(-delta[idx]));
        const float sa = 1.0f / (1.0f + __expf(-alpha[idx]));
        q[n]  = 1.0f - p * sa;                       // decay in (0,1)
        wt[n] = p * beta[idx] * gamma[idx] * 0.25f;  // scale = 1/sqrt(16)
        h[n]  = 0.0f;
    }
    {   // halo warm-up: [max(i0-H,0), i0)
        int start = i0 - HALO; if (start < 0) start = 0;
        #pragma unroll 8
        for (int i = start; i < i0; ++i) {
            const float xv = x[(size_t)i * BD + col];
            #pragma unroll
            for (int n = 0; n < NDIM; ++n) h[n] = fmaf(q[n], h[n], xv);
        }
    }
    // main: emit fwd contribution + residual into acc[]
    #pragma unroll
    for (int j = 0; j < CHUNK; ++j) {
        const float xv = x[(size_t)(i0 + j) * BD + col];
        float a = xv * omega_d;
        #pragma unroll
        for (int n = 0; n < NDIM; ++n) {
            h[n] = fmaf(q[n], h[n], xv);
            a    = fmaf(wt[n], h[n], a);
        }
        acc[j] = a;
    }

    // ============ backward direction: params row DIM+dg ============
    #pragma unroll
    for (int n = 0; n < NDIM; ++n) {
        const int idx = (DIM + dg) * NDIM + n;
        const float p  = 1.0f / (1.0f + __expf(-delta[idx]));
        const float sa = 1.0f / (1.0f + __expf(-alpha[idx]));
        q[n]  = 1.0f - p * sa;
        wt[n] = p * beta[idx] * gamma[idx] * 0.25f;
        h[n]  = 0.0f;
    }
    {   // halo warm-up from the top: (i0+C, min(i0+C+H, L)] descending
        int end = i0 + CHUNK + HALO; if (end > L_SEQ) end = L_SEQ;
        #pragma unroll 8
        for (int i = end - 1; i >= i0 + CHUNK; --i) {
            const float xv = x[(size_t)i * BD + col];
            #pragma unroll
            for (int n = 0; n < NDIM; ++n) h[n] = fmaf(q[n], h[n], xv);
        }
    }
    // main descending: add bwd contribution, store final result
    #pragma unroll
    for (int j = CHUNK - 1; j >= 0; --j) {
        const float xv = x[(size_t)(i0 + j) * BD + col];
        float a = acc[j];
        #pragma unroll
        for (int n = 0; n < NDIM; ++n) {
            h[n] = fmaf(q[n], h[n], xv);
            a    = fmaf(wt[n], h[n], a);
        }
        out[(size_t)(i0 + j) * BD + col] = a;
    }
}

extern "C" void kernel_launch(void* const* d_in, const int* in_sizes, int n_in,
                              void* d_out, int out_size, void* d_ws, size_t ws_size,
                              hipStream_t stream) {
    const float* x     = (const float*)d_in[0];
    const float* delta = (const float*)d_in[1];
    const float* alpha = (const float*)d_in[2];
    const float* beta  = (const float*)d_in[3];
    const float* gamma = (const float*)d_in[4];
    const float* omega = (const float*)d_in[5];
    float* out = (float*)d_out;

    // 16 L-groups x 4 batches x 16 d-tiles = 1024 blocks of 256 threads
    k_ema_fused<<<1024, 256, 0, stream>>>(x, delta, alpha, beta, gamma, omega, out);
}

// Round 7
// 886.227 us; speedup vs baseline: 1.2062x; 1.2062x over previous
//
#include <hip/hip_runtime.h>
#include <math.h>

#define L_SEQ 4096
#define BSZ   4
#define DIM   1024
#define NDIM  16
#define BD    (BSZ*DIM)
#define CHUNK 32      // outputs per wave (32 keeps acc[] in registers, no spill)
#define HALO  64      // warm-up length; q^64 <= 0.008 worst-case -> err ~0.03 << 0.357

// Fused bidirectional 16-state EMA, halo-truncated, no transposes.
// Wave = (b, 64-wide d-tile, 32-long L-chunk). Lane = d within tile, so every
// global access is a coalesced 256B transaction in the native (L,B,D) layout.
// No LDS, no shuffles, no syncthreads - waves fully independent.
// __launch_bounds__(256,4): cap 128 VGPR / guarantee 16 waves/CU - round 6
// showed the unbounded build spills acc[] to scratch (858MB writes, 10% occ).
__global__ __launch_bounds__(256, 4) void k_ema_fused(
    const float* __restrict__ x,
    const float* __restrict__ delta,
    const float* __restrict__ alpha,
    const float* __restrict__ beta,
    const float* __restrict__ gamma,
    const float* __restrict__ omega,
    float* __restrict__ out)
{
    const int lane  = threadIdx.x & 63;
    const int wave  = threadIdx.x >> 6;        // 0..3
    const int dtile = blockIdx.x & 15;         // 16 tiles of 64 d's
    const int b     = (blockIdx.x >> 4) & 3;   // batch
    const int lgrp  = blockIdx.x >> 6;         // 0..31 groups of 4 chunks
    const int chunk = lgrp * 4 + wave;         // 0..127
    const int i0    = chunk * CHUNK;
    const int dg    = dtile * 64 + lane;       // 0..1023
    const int col   = b * DIM + dg;            // column in (L, B*D)

    const float omega_d = omega[dg];

    float acc[CHUNK];
    float h[NDIM], q[NDIM], wt[NDIM];

    // ============ forward direction: params row dg ============
    #pragma unroll
    for (int n = 0; n < NDIM; ++n) {
        const int idx = dg * NDIM + n;
        const float p  = 1.0f / (1.0f + __expf(-delta[idx]));
        const float sa = 1.0f / (1.0f + __expf(-alpha[idx]));
        q[n]  = 1.0f - p * sa;                       // decay in (0,1)
        wt[n] = p * beta[idx] * gamma[idx] * 0.25f;  // scale = 1/sqrt(16)
        h[n]  = 0.0f;
    }
    {   // halo warm-up: [max(i0-H,0), i0)
        int start = i0 - HALO; if (start < 0) start = 0;
        #pragma unroll 8
        for (int i = start; i < i0; ++i) {
            const float xv = x[(size_t)i * BD + col];
            #pragma unroll
            for (int n = 0; n < NDIM; ++n) h[n] = fmaf(q[n], h[n], xv);
        }
    }
    // main: emit fwd contribution + residual into acc[] (full unroll: acc must
    // stay compile-time-indexed or it goes to scratch)
    #pragma unroll
    for (int j = 0; j < CHUNK; ++j) {
        const float xv = x[(size_t)(i0 + j) * BD + col];
        float a = xv * omega_d;
        #pragma unroll
        for (int n = 0; n < NDIM; ++n) {
            h[n] = fmaf(q[n], h[n], xv);
            a    = fmaf(wt[n], h[n], a);
        }
        acc[j] = a;
    }

    // ============ backward direction: params row DIM+dg ============
    #pragma unroll
    for (int n = 0; n < NDIM; ++n) {
        const int idx = (DIM + dg) * NDIM + n;
        const float p  = 1.0f / (1.0f + __expf(-delta[idx]));
        const float sa = 1.0f / (1.0f + __expf(-alpha[idx]));
        q[n]  = 1.0f - p * sa;
        wt[n] = p * beta[idx] * gamma[idx] * 0.25f;
        h[n]  = 0.0f;
    }
    {   // halo warm-up from the top: (i0+C, min(i0+C+H, L)] descending
        int end = i0 + CHUNK + HALO; if (end > L_SEQ) end = L_SEQ;
        #pragma unroll 8
        for (int i = end - 1; i >= i0 + CHUNK; --i) {
            const float xv = x[(size_t)i * BD + col];
            #pragma unroll
            for (int n = 0; n < NDIM; ++n) h[n] = fmaf(q[n], h[n], xv);
        }
    }
    // main descending: add bwd contribution, store final result
    #pragma unroll
    for (int j = CHUNK - 1; j >= 0; --j) {
        const float xv = x[(size_t)(i0 + j) * BD + col];
        float a = acc[j];
        #pragma unroll
        for (int n = 0; n < NDIM; ++n) {
            h[n] = fmaf(q[n], h[n], xv);
            a    = fmaf(wt[n], h[n], a);
        }
        out[(size_t)(i0 + j) * BD + col] = a;
    }
}

extern "C" void kernel_launch(void* const* d_in, const int* in_sizes, int n_in,
                              void* d_out, int out_size, void* d_ws, size_t ws_size,
                              hipStream_t stream) {
    const float* x     = (const float*)d_in[0];
    const float* delta = (const float*)d_in[1];
    const float* alpha = (const float*)d_in[2];
    const float* beta  = (const float*)d_in[3];
    const float* gamma = (const float*)d_in[4];
    const float* omega = (const float*)d_in[5];
    float* out = (float*)d_out;

    // 32 L-groups x 4 batches x 16 d-tiles = 2048 blocks of 256 threads
    k_ema_fused<<<2048, 256, 0, stream>>>(x, delta, alpha, beta, gamma, omega, out);
}

// Round 8
// 82.030 us; speedup vs baseline: 13.0314x; 10.8037x over previous
//
#include <hip/hip_runtime.h>
#include <math.h>

#define L_SEQ 4096
#define BSZ   4
#define DIM   1024
#define NDIM  16
#define BD    (BSZ*DIM)
#define CHUNK 32      // outputs per wave
#define HALO  64      // warm-up length; q^64 <= 0.008 worst-case -> err ~0.03 << 0.357

// Fused bidirectional 16-state EMA, halo-truncated, native (L,B,D) layout.
// Wave = (b, 64-wide d-tile, 32-long L-chunk); lane = d. The fwd partial
// result lives in a per-wave LDS slice (NOT registers - rounds 6/7 showed
// acc[] in VGPRs spills to scratch: 858MB..1.4GB of scratch writes).
// Same wave writes and reads its own slice -> no __syncthreads at all.
__global__ __launch_bounds__(256) void k_ema_fused(
    const float* __restrict__ x,
    const float* __restrict__ delta,
    const float* __restrict__ alpha,
    const float* __restrict__ beta,
    const float* __restrict__ gamma,
    const float* __restrict__ omega,
    float* __restrict__ out)
{
    __shared__ float acc_s[4][CHUNK][64];      // 32 KB; [wave][j][lane] lane-consecutive

    const int lane  = threadIdx.x & 63;
    const int wv    = threadIdx.x >> 6;        // 0..3
    const int dtile = blockIdx.x & 15;         // 16 tiles of 64 d's
    const int b     = (blockIdx.x >> 4) & 3;   // batch
    const int lgrp  = blockIdx.x >> 6;         // 0..31 groups of 4 chunks
    const int chunk = lgrp * 4 + wv;           // 0..127
    const int i0    = chunk * CHUNK;
    const int dg    = dtile * 64 + lane;       // 0..1023
    const int col   = b * DIM + dg;            // column in (L, B*D)

    const float omega_d = omega[dg];

    float h[NDIM], q[NDIM], wt[NDIM];

    // ============ forward direction: params row dg ============
    #pragma unroll
    for (int n = 0; n < NDIM; ++n) {
        const int idx = dg * NDIM + n;
        const float p  = 1.0f / (1.0f + __expf(-delta[idx]));
        const float sa = 1.0f / (1.0f + __expf(-alpha[idx]));
        q[n]  = 1.0f - p * sa;                       // decay in (0,1)
        wt[n] = p * beta[idx] * gamma[idx] * 0.25f;  // scale = 1/sqrt(16)
        h[n]  = 0.0f;
    }
    {   // halo warm-up: [max(i0-H,0), i0)
        int start = i0 - HALO; if (start < 0) start = 0;
        #pragma unroll 8
        for (int i = start; i < i0; ++i) {
            const float xv = x[(size_t)i * BD + col];
            #pragma unroll
            for (int n = 0; n < NDIM; ++n) h[n] = fmaf(q[n], h[n], xv);
        }
    }
    // main fwd: emit fwd contribution + residual into the LDS slice
    #pragma unroll 8
    for (int j = 0; j < CHUNK; ++j) {
        const float xv = x[(size_t)(i0 + j) * BD + col];
        float a = xv * omega_d;
        #pragma unroll
        for (int n = 0; n < NDIM; ++n) {
            h[n] = fmaf(q[n], h[n], xv);
            a    = fmaf(wt[n], h[n], a);
        }
        acc_s[wv][j][lane] = a;
    }

    // ============ backward direction: params row DIM+dg ============
    #pragma unroll
    for (int n = 0; n < NDIM; ++n) {
        const int idx = (DIM + dg) * NDIM + n;
        const float p  = 1.0f / (1.0f + __expf(-delta[idx]));
        const float sa = 1.0f / (1.0f + __expf(-alpha[idx]));
        q[n]  = 1.0f - p * sa;
        wt[n] = p * beta[idx] * gamma[idx] * 0.25f;
        h[n]  = 0.0f;
    }
    {   // halo warm-up from the top: descending into i0+CHUNK
        int end = i0 + CHUNK + HALO; if (end > L_SEQ) end = L_SEQ;
        #pragma unroll 8
        for (int i = end - 1; i >= i0 + CHUNK; --i) {
            const float xv = x[(size_t)i * BD + col];
            #pragma unroll
            for (int n = 0; n < NDIM; ++n) h[n] = fmaf(q[n], h[n], xv);
        }
    }
    // main bwd descending: add bwd contribution to LDS value, store result
    #pragma unroll 8
    for (int j = CHUNK - 1; j >= 0; --j) {
        const float xv = x[(size_t)(i0 + j) * BD + col];
        float a = acc_s[wv][j][lane];
        #pragma unroll
        for (int n = 0; n < NDIM; ++n) {
            h[n] = fmaf(q[n], h[n], xv);
            a    = fmaf(wt[n], h[n], a);
        }
        out[(size_t)(i0 + j) * BD + col] = a;
    }
}

extern "C" void kernel_launch(void* const* d_in, const int* in_sizes, int n_in,
                              void* d_out, int out_size, void* d_ws, size_t ws_size,
                              hipStream_t stream) {
    const float* x     = (const float*)d_in[0];
    const float* delta = (const float*)d_in[1];
    const float* alpha = (const float*)d_in[2];
    const float* beta  = (const float*)d_in[3];
    const float* gamma = (const float*)d_in[4];
    const float* omega = (const float*)d_in[5];
    float* out = (float*)d_out;

    // 32 L-groups x 4 batches x 16 d-tiles = 2048 blocks of 256 threads
    k_ema_fused<<<2048, 256, 0, stream>>>(x, delta, alpha, beta, gamma, omega, out);
}